// Round 1
// baseline (624.916 us; speedup 1.0000x reference)
//
#include <hip/hip_runtime.h>

#define SEQ 128
#define BATCH 512
#define IN_DIM 128
#define HID 128

__device__ __forceinline__ float sigmoid_f(float x) { return 1.0f / (1.0f + __expf(-x)); }
__device__ __forceinline__ float tanh_f(float x) { return 1.0f - 2.0f / (__expf(2.0f * x) + 1.0f); }

// One block per batch element; 4 waves, wave g simulates gate g (f,i,g,o).
// State: 256 complex amps as 2 real vectors; 64 lanes x 4 values/lane.
// b index bits: [7:2] = lane bits [5:0], [1:0] = register index j.
__global__ __launch_bounds__(256) void qlstm_kernel(
    const float* __restrict__ X,  const float* __restrict__ Wq, const float* __restrict__ bq,
    const float* __restrict__ pf, const float* __restrict__ pi_, const float* __restrict__ pg,
    const float* __restrict__ po, const float* __restrict__ Wf, const float* __restrict__ bf,
    const float* __restrict__ Wi, const float* __restrict__ bi, const float* __restrict__ Wg,
    const float* __restrict__ bg, const float* __restrict__ Wo, const float* __restrict__ bo,
    float* __restrict__ out)
{
  __shared__ float wq_sh[8 * 256];      // first 8 rows of Wq (rows 8..31 unused by _qgate)
  __shared__ float wgt_sh[4 * 8 * 128]; // per-gate W transposed to [w][h] (bank-conflict free)
  __shared__ float bias_sh[4 * 128];
  __shared__ float bq_sh[8];
  __shared__ float h_sh[128];
  __shared__ float gates_sh[4 * 128];
  __shared__ float qin_sh[8];

  const int tid  = threadIdx.x;
  const int lane = tid & 63;
  const int wv   = tid >> 6;
  const int b    = blockIdx.x;

  // ---- one-time preload ----
  for (int i = tid; i < 2048; i += 256) wq_sh[i] = Wq[i];
  const float* gW = (wv == 0) ? Wf : (wv == 1) ? Wi : (wv == 2) ? Wg : Wo;
  const float* gB = (wv == 0) ? bf : (wv == 1) ? bi : (wv == 2) ? bg : bo;
  const float* gP = (wv == 0) ? pf : (wv == 1) ? pi_ : (wv == 2) ? pg : po;
  for (int i = lane; i < 1024; i += 64) {
    int h = i >> 3, w = i & 7;
    wgt_sh[wv * 1024 + w * 128 + h] = gW[i];
  }
  for (int i = lane; i < 128; i += 64) bias_sh[wv * 128 + i] = gB[i];
  if (tid < 8) bq_sh[tid] = bq[tid];
  if (tid < 128) h_sh[tid] = 0.0f;

  // per-gate RY angle constants (params are data-independent of t,b)
  float cb0[8], sb0[8], cb1[8], sb1[8];
#pragma unroll
  for (int v = 0; v < 8; ++v) {
    float b0 = gP[v], b1 = gP[8 + v];
    cb0[v] = cosf(0.5f * b0); sb0[v] = sinf(0.5f * b0);
    cb1[v] = cosf(0.5f * b1); sb1[v] = sinf(0.5f * b1);
  }
  // prefix-parity signs over lane bits 5..(5-w)  (== b bits 7..(7-w))
  float sg[6];
  { int par = 0;
#pragma unroll
    for (int w = 0; w < 6; ++w) { par ^= (lane >> (5 - w)) & 1; sg[w] = par ? -1.0f : 1.0f; }
  }

  float c_reg = 0.0f;
  __syncthreads();

  const int w0 = wv * 2, w1 = w0 + 1;

  for (int t = 0; t < SEQ; ++t) {
    // ---- q_in[w] = [x,h] . Wq[w] + bq[w]  (wave wv computes w0,w1) ----
    const float* xp = X + ((size_t)t * BATCH + b) * IN_DIM;
    float xv0 = xp[lane], xv1 = xp[lane + 64];
    float hv0 = h_sh[lane], hv1 = h_sh[lane + 64];
    float a0 = xv0 * wq_sh[w0 * 256 + lane]       + xv1 * wq_sh[w0 * 256 + 64 + lane]
             + hv0 * wq_sh[w0 * 256 + 128 + lane] + hv1 * wq_sh[w0 * 256 + 192 + lane];
    float a1 = xv0 * wq_sh[w1 * 256 + lane]       + xv1 * wq_sh[w1 * 256 + 64 + lane]
             + hv0 * wq_sh[w1 * 256 + 128 + lane] + hv1 * wq_sh[w1 * 256 + 192 + lane];
#pragma unroll
    for (int off = 1; off < 64; off <<= 1) {
      a0 += __shfl_xor(a0, off, 64);
      a1 += __shfl_xor(a1, off, 64);
    }
    if (lane == 0) { qin_sh[w0] = a0 + bq_sh[w0]; qin_sh[w1] = a1 + bq_sh[w1]; }
    __syncthreads();

    // ---- build product state  psi1 = Ry(layer0) . RX(theta) |0> ----
    // per-qubit spinor: a0=(cb*c, sb*s), a1=(sb*c, -cb*s); amplitude = product
    float re[4], im[4];
    {
      float Pre, Pim;
      {
        float s, c; __sincosf(0.5f * qin_sh[0], &s, &c);
        int bit = (lane >> 5) & 1;
        Pre = bit ? sb0[0] * c : cb0[0] * c;
        Pim = bit ? -cb0[0] * s : sb0[0] * s;
      }
#pragma unroll
      for (int v = 1; v < 6; ++v) {
        float s, c; __sincosf(0.5f * qin_sh[v], &s, &c);
        int bit = (lane >> (5 - v)) & 1;
        float fre = bit ? sb0[v] * c : cb0[v] * c;
        float fim = bit ? -cb0[v] * s : sb0[v] * s;
        float nre = Pre * fre - Pim * fim;
        float nim = Pre * fim + Pim * fre;
        Pre = nre; Pim = nim;
      }
      float s6, c6, s7, c7;
      __sincosf(0.5f * qin_sh[6], &s6, &c6);
      __sincosf(0.5f * qin_sh[7], &s7, &c7);
      float a06re = cb0[6] * c6, a06im =  sb0[6] * s6;
      float a16re = sb0[6] * c6, a16im = -cb0[6] * s6;
      float a07re = cb0[7] * c7, a07im =  sb0[7] * s7;
      float a17re = sb0[7] * c7, a17im = -cb0[7] * s7;
      float Q0re = Pre * a06re - Pim * a06im, Q0im = Pre * a06im + Pim * a06re;
      float Q1re = Pre * a16re - Pim * a16im, Q1im = Pre * a16im + Pim * a16re;
      re[0] = Q0re * a07re - Q0im * a07im; im[0] = Q0re * a07im + Q0im * a07re;
      re[1] = Q0re * a17re - Q0im * a17im; im[1] = Q0re * a17im + Q0im * a17re;
      re[2] = Q1re * a07re - Q1im * a07im; im[2] = Q1re * a07im + Q1im * a07re;
      re[3] = Q1re * a17re - Q1im * a17im; im[3] = Q1re * a17im + Q1im * a17re;
    }

    // ---- CNOT chain: new[b] = old[b ^ (1<<pt)] if control bit set ----
#pragma unroll
    for (int w = 0; w < 5; ++w) {
      int cbit = 5 - w;        // control = lane bit (5-w)
      int mk   = 1 << (4 - w); // partner lane mask (target lane bit)
      bool take = (lane >> cbit) & 1;
#pragma unroll
      for (int j = 0; j < 4; ++j) {
        float pr = __shfl_xor(re[j], mk, 64);
        float pm = __shfl_xor(im[j], mk, 64);
        re[j] = take ? pr : re[j];
        im[j] = take ? pm : im[j];
      }
    }
    { // w=5: control = lane bit 0, target = j bit 1 -> swap j <-> j^2
      bool c5 = lane & 1;
      float r0 = c5 ? re[2] : re[0], r2 = c5 ? re[0] : re[2];
      float r1 = c5 ? re[3] : re[1], r3 = c5 ? re[1] : re[3];
      float i0 = c5 ? im[2] : im[0], i2 = c5 ? im[0] : im[2];
      float i1 = c5 ? im[3] : im[1], i3 = c5 ? im[1] : im[3];
      re[0] = r0; re[1] = r1; re[2] = r2; re[3] = r3;
      im[0] = i0; im[1] = i1; im[2] = i2; im[3] = i3;
    }
    { // w=6: control = j bit1, target = j bit0 -> swap j2<->j3 (free rename)
      float tr = re[2]; re[2] = re[3]; re[3] = tr;
      float ti = im[2]; im[2] = im[3]; im[3] = ti;
    }

    // ---- RY layer d=1 ----
#pragma unroll
    for (int v = 0; v < 6; ++v) {
      int lb = 5 - v;
      int mk = 1 << lb;
      float cc  = cb1[v];
      float sgn = ((lane >> lb) & 1) ? sb1[v] : -sb1[v];
#pragma unroll
      for (int j = 0; j < 4; ++j) {
        float pr = __shfl_xor(re[j], mk, 64);
        float pm = __shfl_xor(im[j], mk, 64);
        re[j] = cc * re[j] + sgn * pr;
        im[j] = cc * im[j] + sgn * pm;
      }
    }
    { // v=6: pairs (0,2),(1,3)
      float cc = cb1[6], ss = sb1[6];
      float n0 = cc*re[0] - ss*re[2], n2 = ss*re[0] + cc*re[2];
      float n1 = cc*re[1] - ss*re[3], n3 = ss*re[1] + cc*re[3];
      re[0]=n0; re[1]=n1; re[2]=n2; re[3]=n3;
      float m0 = cc*im[0] - ss*im[2], m2 = ss*im[0] + cc*im[2];
      float m1 = cc*im[1] - ss*im[3], m3 = ss*im[1] + cc*im[3];
      im[0]=m0; im[1]=m1; im[2]=m2; im[3]=m3;
    }
    { // v=7: pairs (0,1),(2,3)
      float cc = cb1[7], ss = sb1[7];
      float n0 = cc*re[0] - ss*re[1], n1 = ss*re[0] + cc*re[1];
      float n2 = cc*re[2] - ss*re[3], n3 = ss*re[2] + cc*re[3];
      re[0]=n0; re[1]=n1; re[2]=n2; re[3]=n3;
      float m0 = cc*im[0] - ss*im[1], m1 = ss*im[0] + cc*im[1];
      float m2 = cc*im[2] - ss*im[3], m3 = ss*im[2] + cc*im[3];
      im[0]=m0; im[1]=m1; im[2]=m2; im[3]=m3;
    }

    // ---- probs + expvals; final CNOT chain folded: <Z_w> -> prefix parity ----
    float p0 = re[0]*re[0] + im[0]*im[0];
    float p1 = re[1]*re[1] + im[1]*im[1];
    float p2 = re[2]*re[2] + im[2]*im[2];
    float p3 = re[3]*re[3] + im[3]*im[3];
    float t01 = p0 + p1, t23 = p2 + p3;
    float S = t01 + t23;
    float ev[8];
    ev[0] = sg[0] * S; ev[1] = sg[1] * S; ev[2] = sg[2] * S;
    ev[3] = sg[3] * S; ev[4] = sg[4] * S; ev[5] = sg[5] * S;
    ev[6] = sg[5] * (t01 - t23);
    ev[7] = sg[5] * ((p0 - p1) - (p2 - p3));
#pragma unroll
    for (int off = 1; off < 64; off <<= 1) {
#pragma unroll
      for (int w = 0; w < 8; ++w) ev[w] += __shfl_xor(ev[w], off, 64);
    }

    // ---- gate linear (8 -> 128) + activation ----
#pragma unroll
    for (int r = 0; r < 2; ++r) {
      int h = lane + 64 * r;
      float acc = bias_sh[wv * 128 + h];
#pragma unroll
      for (int w = 0; w < 8; ++w) acc += ev[w] * wgt_sh[wv * 1024 + w * 128 + h];
      gates_sh[wv * 128 + h] = (wv == 2) ? tanh_f(acc) : sigmoid_f(acc);
    }
    __syncthreads();

    // ---- LSTM cell update ----
    if (tid < 128) {
      float f  = gates_sh[tid];
      float ii = gates_sh[128 + tid];
      float gg = gates_sh[256 + tid];
      float oo = gates_sh[384 + tid];
      c_reg = f * c_reg + ii * gg;
      float hn = oo * tanh_f(c_reg);
      h_sh[tid] = hn;
      out[((size_t)t * BATCH + b) * HID + tid] = hn;
    }
    __syncthreads();
  }

  if (tid < 128) {
    size_t base = (size_t)SEQ * BATCH * HID;
    out[base + (size_t)b * HID + tid] = h_sh[tid];                       // hx
    out[base + (size_t)BATCH * HID + (size_t)b * HID + tid] = c_reg;     // cx
  }
}

extern "C" void kernel_launch(void* const* d_in, const int* in_sizes, int n_in,
                              void* d_out, int out_size, void* d_ws, size_t ws_size,
                              hipStream_t stream) {
  (void)in_sizes; (void)n_in; (void)out_size; (void)d_ws; (void)ws_size;
  const float* X   = (const float*)d_in[0];
  const float* Wq  = (const float*)d_in[1];
  const float* bq  = (const float*)d_in[2];
  const float* pf  = (const float*)d_in[3];
  const float* pi_ = (const float*)d_in[4];
  const float* pg  = (const float*)d_in[5];
  const float* po  = (const float*)d_in[6];
  const float* Wf  = (const float*)d_in[7];
  const float* bf  = (const float*)d_in[8];
  const float* Wi  = (const float*)d_in[9];
  const float* bi  = (const float*)d_in[10];
  const float* Wg  = (const float*)d_in[11];
  const float* bg  = (const float*)d_in[12];
  const float* Wo  = (const float*)d_in[13];
  const float* bo  = (const float*)d_in[14];
  float* out = (float*)d_out;

  qlstm_kernel<<<BATCH, 256, 0, stream>>>(X, Wq, bq, pf, pi_, pg, po,
                                          Wf, bf, Wi, bi, Wg, bg, Wo, bo, out);
}

// Round 2
// 409.916 us; speedup vs baseline: 1.5245x; 1.5245x over previous
//
#include <hip/hip_runtime.h>

#define SEQ 128
#define BATCH 512
#define IN_DIM 128
#define HID 128

__device__ __forceinline__ float sigmoid_f(float x) { return 1.0f / (1.0f + __expf(-x)); }
__device__ __forceinline__ float tanh_f(float x) { return 1.0f - 2.0f / (__expf(2.0f * x) + 1.0f); }

// DPP quad_perm lane swaps (VALU pipe, not LDS): xor1 = [1,0,3,2] = 0xB1, xor2 = [2,3,0,1] = 0x4E
__device__ __forceinline__ float dpp_xor1(float x) {
  return __int_as_float(__builtin_amdgcn_mov_dpp(__float_as_int(x), 0xB1, 0xF, 0xF, true));
}
__device__ __forceinline__ float dpp_xor2(float x) {
  return __int_as_float(__builtin_amdgcn_mov_dpp(__float_as_int(x), 0x4E, 0xF, 0xF, true));
}
__device__ __forceinline__ float bperm_f(int addr, float x) {
  return __int_as_float(__builtin_amdgcn_ds_bpermute(addr, __float_as_int(x)));
}

// Wave-wide sum of 8 per-lane values, result (canonical order) in all lanes.
// Reduce-scatter (masks 1,2 on DPP; 4,8,16,32 on ds) + allgather (4 ds=1, 2/1 DPP).
// Total: 5 ds ops + 12 DPP (vs 48 ds for naive butterfly).
__device__ __forceinline__ void wave_sum8(float v[8], int lane) {
  const bool c0 = lane & 1, c1 = lane & 2, c2 = lane & 4;
  float w[4];
#pragma unroll
  for (int k = 0; k < 4; ++k) {
    float mine = c0 ? v[4 + k] : v[k];
    float send = c0 ? v[k] : v[4 + k];
    w[k] = mine + dpp_xor1(send);
  }
  float u[2];
#pragma unroll
  for (int k = 0; k < 2; ++k) {
    float mine = c1 ? w[2 + k] : w[k];
    float send = c1 ? w[k] : w[2 + k];
    u[k] = mine + dpp_xor2(send);
  }
  float mine = c2 ? u[1] : u[0];
  float send = c2 ? u[0] : u[1];
  float z = mine + __shfl_xor(send, 4, 64);
  z += __shfl_xor(z, 8, 64);
  z += __shfl_xor(z, 16, 64);
  z += __shfl_xor(z, 32, 64);
  // allgather back to canonical order
  float p = __shfl_xor(z, 4, 64);
  float t0 = c2 ? p : z, t1 = c2 ? z : p;          // t[j] = q[j + 2b1 + 4b0]
  float r0 = dpp_xor2(t0), r1 = dpp_xor2(t1);
  float u0 = c1 ? r0 : t0, u1 = c1 ? r1 : t1;      // u[j] = q[j + 4b0]
  float u2 = c1 ? t0 : r0, u3 = c1 ? t1 : r1;
  float s0 = dpp_xor1(u0), s1 = dpp_xor1(u1), s2 = dpp_xor1(u2), s3 = dpp_xor1(u3);
  v[0] = c0 ? s0 : u0; v[1] = c0 ? s1 : u1; v[2] = c0 ? s2 : u2; v[3] = c0 ? s3 : u3;
  v[4] = c0 ? u0 : s0; v[5] = c0 ? u1 : s1; v[6] = c0 ? u2 : s2; v[7] = c0 ? u3 : s3;
}

// One block per batch element; wave wv simulates gate wv (f,i,g,o).
// 256 amps = 64 lanes x 4 regs; b bits [7:2]=lane[5:0], [1:0]=reg j.
// h,c replicated in registers of every wave; 1 barrier/timestep (gates exchange).
__global__ __launch_bounds__(256) void qlstm_kernel(
    const float* __restrict__ X,  const float* __restrict__ Wq, const float* __restrict__ bq,
    const float* __restrict__ pf, const float* __restrict__ pi_, const float* __restrict__ pg,
    const float* __restrict__ po, const float* __restrict__ Wf, const float* __restrict__ bf,
    const float* __restrict__ Wi, const float* __restrict__ bi, const float* __restrict__ Wg,
    const float* __restrict__ bg, const float* __restrict__ Wo, const float* __restrict__ bo,
    float* __restrict__ out)
{
  __shared__ float gates_sh[2][4 * 128];   // double-buffered by t parity

  const int tid  = threadIdx.x;
  const int lane = tid & 63;
  const int wv   = tid >> 6;
  const int b    = blockIdx.x;

  const float* gW = (wv == 0) ? Wf : (wv == 1) ? Wi : (wv == 2) ? Wg : Wo;
  const float* gB = (wv == 0) ? bf : (wv == 1) ? bi : (wv == 2) ? bg : bo;
  const float* gP = (wv == 0) ? pf : (wv == 1) ? pi_ : (wv == 2) ? pg : po;

  // ---- one-time register preloads ----
  float wqr[8][4];           // Wq rows 0..7 (rows 8..31 dead), cols {lane+64k}
#pragma unroll
  for (int w = 0; w < 8; ++w)
#pragma unroll
    for (int k = 0; k < 4; ++k) wqr[w][k] = Wq[w * 256 + lane + 64 * k];
  float bqr[8];
#pragma unroll
  for (int w = 0; w < 8; ++w) bqr[w] = bq[w];
  float wgr[2][8];           // gate weights W[h][w] for h = lane, lane+64
#pragma unroll
  for (int r = 0; r < 2; ++r)
#pragma unroll
    for (int w = 0; w < 8; ++w) wgr[r][w] = gW[(lane + 64 * r) * 8 + w];
  float br2[2] = { gB[lane], gB[lane + 64] };

  // RY angle constants
  float cb0[8], sb0[8], cb1[8], sb1[8];
#pragma unroll
  for (int v = 0; v < 8; ++v) {
    float a0 = gP[v], a1 = gP[8 + v];
    cb0[v] = cosf(0.5f * a0); sb0[v] = sinf(0.5f * a0);
    cb1[v] = cosf(0.5f * a1); sb1[v] = sinf(0.5f * a1);
  }
  // prefix-parity signs over lane bits 5..(5-w)
  float sg[6];
  { int par = 0;
#pragma unroll
    for (int w = 0; w < 6; ++w) { par ^= (lane >> (5 - w)) & 1; sg[w] = par ? -1.0f : 1.0f; }
  }
  // CNOT-chain-as-permutation: src lane = Gray code of lane; byte addr for bpermute
  const int bp_addr = (lane ^ (lane >> 1)) << 2;
  const bool odd = lane & 1;

  float c0r = 0.0f, c1r = 0.0f, h0r = 0.0f, h1r = 0.0f;

  // x prefetch
  float nx0 = X[(size_t)b * IN_DIM + lane];
  float nx1 = X[(size_t)b * IN_DIM + lane + 64];

#pragma unroll 1
  for (int t = 0; t < SEQ; ++t) {
    float xv0 = nx0, xv1 = nx1;
    if (t + 1 < SEQ) {
      const float* xn = X + ((size_t)(t + 1) * BATCH + b) * IN_DIM;
      nx0 = xn[lane]; nx1 = xn[lane + 64];
    }

    // ---- q_in (all 8 wires, redundantly per wave; h from registers) ----
    float q[8];
#pragma unroll
    for (int w = 0; w < 8; ++w)
      q[w] = xv0 * wqr[w][0] + xv1 * wqr[w][1] + h0r * wqr[w][2] + h1r * wqr[w][3];
    wave_sum8(q, lane);
#pragma unroll
    for (int w = 0; w < 8; ++w) q[w] += bqr[w];

    // ---- product state  psi = Ry(layer0) . RX(theta) |0> ----
    float re[4], im[4];
    {
      float Pre, Pim;
      {
        float s, c; __sincosf(0.5f * q[0], &s, &c);
        int bit = (lane >> 5) & 1;
        Pre = bit ? sb0[0] * c : cb0[0] * c;
        Pim = bit ? -cb0[0] * s : sb0[0] * s;
      }
#pragma unroll
      for (int v = 1; v < 6; ++v) {
        float s, c; __sincosf(0.5f * q[v], &s, &c);
        int bit = (lane >> (5 - v)) & 1;
        float fre = bit ? sb0[v] * c : cb0[v] * c;
        float fim = bit ? -cb0[v] * s : sb0[v] * s;
        float nre = Pre * fre - Pim * fim;
        float nim = Pre * fim + Pim * fre;
        Pre = nre; Pim = nim;
      }
      float s6, c6, s7, c7;
      __sincosf(0.5f * q[6], &s6, &c6);
      __sincosf(0.5f * q[7], &s7, &c7);
      float a06re = cb0[6] * c6, a06im =  sb0[6] * s6;
      float a16re = sb0[6] * c6, a16im = -cb0[6] * s6;
      float a07re = cb0[7] * c7, a07im =  sb0[7] * s7;
      float a17re = sb0[7] * c7, a17im = -cb0[7] * s7;
      float Q0re = Pre * a06re - Pim * a06im, Q0im = Pre * a06im + Pim * a06re;
      float Q1re = Pre * a16re - Pim * a16im, Q1im = Pre * a16im + Pim * a16re;
      re[0] = Q0re * a07re - Q0im * a07im; im[0] = Q0re * a07im + Q0im * a07re;
      re[1] = Q0re * a17re - Q0im * a17im; im[1] = Q0re * a17im + Q0im * a17re;
      re[2] = Q1re * a07re - Q1im * a07im; im[2] = Q1re * a07im + Q1im * a07re;
      re[3] = Q1re * a17re - Q1im * a17im; im[3] = Q1re * a17im + Q1im * a17re;
    }

    // ---- full CNOT chain as ONE permutation: new[c] = old[gray(c)] ----
    // src lane = lane ^ (lane>>1); reg map: even {0,1,3,2}, odd {2,3,1,0}
    {
      float tr0 = bperm_f(bp_addr, re[0]), tr1 = bperm_f(bp_addr, re[1]);
      float tr2 = bperm_f(bp_addr, re[2]), tr3 = bperm_f(bp_addr, re[3]);
      float ti0 = bperm_f(bp_addr, im[0]), ti1 = bperm_f(bp_addr, im[1]);
      float ti2 = bperm_f(bp_addr, im[2]), ti3 = bperm_f(bp_addr, im[3]);
      re[0] = odd ? tr2 : tr0; re[1] = odd ? tr3 : tr1;
      re[2] = odd ? tr1 : tr3; re[3] = odd ? tr0 : tr2;
      im[0] = odd ? ti2 : ti0; im[1] = odd ? ti3 : ti1;
      im[2] = odd ? ti1 : ti3; im[3] = odd ? ti0 : ti2;
    }

    // ---- RY layer d=1 ----
#pragma unroll
    for (int v = 0; v < 4; ++v) {         // wires 0..3: lane masks 32,16,8,4 (ds)
      int lb = 5 - v;
      int mk = 1 << lb;
      float cc  = cb1[v];
      float sgn = ((lane >> lb) & 1) ? sb1[v] : -sb1[v];
#pragma unroll
      for (int j = 0; j < 4; ++j) {
        float pr = __shfl_xor(re[j], mk, 64);
        float pm = __shfl_xor(im[j], mk, 64);
        re[j] = cc * re[j] + sgn * pr;
        im[j] = cc * im[j] + sgn * pm;
      }
    }
    { // wire 4: mask 2 via DPP
      float cc = cb1[4], sgn = (lane & 2) ? sb1[4] : -sb1[4];
#pragma unroll
      for (int j = 0; j < 4; ++j) {
        float pr = dpp_xor2(re[j]), pm = dpp_xor2(im[j]);
        re[j] = cc * re[j] + sgn * pr;
        im[j] = cc * im[j] + sgn * pm;
      }
    }
    { // wire 5: mask 1 via DPP
      float cc = cb1[5], sgn = (lane & 1) ? sb1[5] : -sb1[5];
#pragma unroll
      for (int j = 0; j < 4; ++j) {
        float pr = dpp_xor1(re[j]), pm = dpp_xor1(im[j]);
        re[j] = cc * re[j] + sgn * pr;
        im[j] = cc * im[j] + sgn * pm;
      }
    }
    { // wire 6: regs (0,2),(1,3)
      float cc = cb1[6], ss = sb1[6];
      float n0 = cc*re[0] - ss*re[2], n2 = ss*re[0] + cc*re[2];
      float n1 = cc*re[1] - ss*re[3], n3 = ss*re[1] + cc*re[3];
      re[0]=n0; re[1]=n1; re[2]=n2; re[3]=n3;
      float m0 = cc*im[0] - ss*im[2], m2 = ss*im[0] + cc*im[2];
      float m1 = cc*im[1] - ss*im[3], m3 = ss*im[1] + cc*im[3];
      im[0]=m0; im[1]=m1; im[2]=m2; im[3]=m3;
    }
    { // wire 7: regs (0,1),(2,3)
      float cc = cb1[7], ss = sb1[7];
      float n0 = cc*re[0] - ss*re[1], n1 = ss*re[0] + cc*re[1];
      float n2 = cc*re[2] - ss*re[3], n3 = ss*re[2] + cc*re[3];
      re[0]=n0; re[1]=n1; re[2]=n2; re[3]=n3;
      float m0 = cc*im[0] - ss*im[1], m1 = ss*im[0] + cc*im[1];
      float m2 = cc*im[2] - ss*im[3], m3 = ss*im[2] + cc*im[3];
      im[0]=m0; im[1]=m1; im[2]=m2; im[3]=m3;
    }

    // ---- probs; final CNOT chain folded into prefix-parity signs ----
    float p0 = re[0]*re[0] + im[0]*im[0];
    float p1 = re[1]*re[1] + im[1]*im[1];
    float p2 = re[2]*re[2] + im[2]*im[2];
    float p3 = re[3]*re[3] + im[3]*im[3];
    float t01 = p0 + p1, t23 = p2 + p3;
    float S = t01 + t23;
    float ev[8];
    ev[0] = sg[0] * S; ev[1] = sg[1] * S; ev[2] = sg[2] * S;
    ev[3] = sg[3] * S; ev[4] = sg[4] * S; ev[5] = sg[5] * S;
    ev[6] = sg[5] * (t01 - t23);
    ev[7] = sg[5] * ((p0 - p1) - (p2 - p3));
    wave_sum8(ev, lane);

    // ---- gate linear (8 -> 128, weights in regs) + activation ----
    float* gbuf = gates_sh[t & 1];
#pragma unroll
    for (int r = 0; r < 2; ++r) {
      float acc = br2[r];
#pragma unroll
      for (int w = 0; w < 8; ++w) acc += ev[w] * wgr[r][w];
      gbuf[wv * 128 + lane + 64 * r] = (wv == 2) ? tanh_f(acc) : sigmoid_f(acc);
    }
    __syncthreads();

    // ---- LSTM cell update, replicated in every wave (h,c stay in regs) ----
    float f0 = gbuf[lane],        f1 = gbuf[lane + 64];
    float i0 = gbuf[128 + lane],  i1 = gbuf[128 + lane + 64];
    float g0 = gbuf[256 + lane],  g1 = gbuf[256 + lane + 64];
    float o0 = gbuf[384 + lane],  o1 = gbuf[384 + lane + 64];
    c0r = f0 * c0r + i0 * g0;
    c1r = f1 * c1r + i1 * g1;
    h0r = o0 * tanh_f(c0r);
    h1r = o1 * tanh_f(c1r);

    if (wv == 0) {
      float* op = out + ((size_t)t * BATCH + b) * HID;
      op[lane] = h0r; op[lane + 64] = h1r;
    }
  }

  if (wv == 0) {
    size_t base = (size_t)SEQ * BATCH * HID;
    out[base + (size_t)b * HID + lane] = h0r;
    out[base + (size_t)b * HID + lane + 64] = h1r;
    out[base + (size_t)BATCH * HID + (size_t)b * HID + lane] = c0r;
    out[base + (size_t)BATCH * HID + (size_t)b * HID + lane + 64] = c1r;
  }
}

extern "C" void kernel_launch(void* const* d_in, const int* in_sizes, int n_in,
                              void* d_out, int out_size, void* d_ws, size_t ws_size,
                              hipStream_t stream) {
  (void)in_sizes; (void)n_in; (void)out_size; (void)d_ws; (void)ws_size;
  const float* X   = (const float*)d_in[0];
  const float* Wq  = (const float*)d_in[1];
  const float* bq  = (const float*)d_in[2];
  const float* pf  = (const float*)d_in[3];
  const float* pi_ = (const float*)d_in[4];
  const float* pg  = (const float*)d_in[5];
  const float* po  = (const float*)d_in[6];
  const float* Wf  = (const float*)d_in[7];
  const float* bf  = (const float*)d_in[8];
  const float* Wi  = (const float*)d_in[9];
  const float* bi  = (const float*)d_in[10];
  const float* Wg  = (const float*)d_in[11];
  const float* bg  = (const float*)d_in[12];
  const float* Wo  = (const float*)d_in[13];
  const float* bo  = (const float*)d_in[14];
  float* out = (float*)d_out;

  qlstm_kernel<<<BATCH, 256, 0, stream>>>(X, Wq, bq, pf, pi_, pg, po,
                                          Wf, bf, Wi, bi, Wg, bg, Wo, bo, out);
}

// Round 4
// 257.706 us; speedup vs baseline: 2.4249x; 1.5906x over previous
//
#include <hip/hip_runtime.h>

#define SEQ 128
#define BATCH 512
#define IN_DIM 128
#define HID 128

__device__ __forceinline__ float sigmoid_f(float x) { return 1.0f / (1.0f + __expf(-x)); }
__device__ __forceinline__ float tanh_f(float x) { return 1.0f - 2.0f / (__expf(2.0f * x) + 1.0f); }

// DPP quad_perm lane swaps (VALU pipe): xor1 = [1,0,3,2] = 0xB1, xor2 = [2,3,0,1] = 0x4E
__device__ __forceinline__ float dpp_xor1(float x) {
  return __int_as_float(__builtin_amdgcn_mov_dpp(__float_as_int(x), 0xB1, 0xF, 0xF, true));
}
__device__ __forceinline__ float dpp_xor2(float x) {
  return __int_as_float(__builtin_amdgcn_mov_dpp(__float_as_int(x), 0x4E, 0xF, 0xF, true));
}

// Reduce-scatter of 8 per-lane partials: lane (b2 b1 b0 = low bits) ends up
// holding the full wave-sum of v[4*b0 + 2*b1 + b2]. 4 ds shuffles + 6 DPP.
__device__ __forceinline__ float reduce8_scatter(const float v[8], int lane) {
  const bool c0 = lane & 1, c1 = lane & 2, c2 = lane & 4;
  float w[4];
#pragma unroll
  for (int k = 0; k < 4; ++k) {
    float mine = c0 ? v[4 + k] : v[k];
    float send = c0 ? v[k] : v[4 + k];
    w[k] = mine + dpp_xor1(send);
  }
  float u[2];
#pragma unroll
  for (int k = 0; k < 2; ++k) {
    float mine = c1 ? w[2 + k] : w[k];
    float send = c1 ? w[k] : w[2 + k];
    u[k] = mine + dpp_xor2(send);
  }
  float mine = c2 ? u[1] : u[0];
  float send = c2 ? u[0] : u[1];
  float z = mine + __shfl_xor(send, 4, 64);
  z += __shfl_xor(z, 8, 64);
  z += __shfl_xor(z, 16, 64);
  z += __shfl_xor(z, 32, 64);
  return z;
}

// One block per batch element; wave wv handles gate wv (f,i,g,o).
//
// Quantum circuit in closed form: exact 4-dim transfer-matrix recursion over
// the pairwise density sigma(alpha,alpha') with state (u,d,P,R):
//   u = s00 - s11, d = s00 + s11, s01 = (P + i R)/2.
// Per wire w: K = cos(b0)cos(q), A2 = sin(b0)cos(q), B2 = sin(q),
//             C = cos(b1), S = sin(b1):
//   M_u = K*u - B2*R;  M_d = d + A2*P;  M_P = A2*d + P;  M_R = B2*u + K*R
//   u' = C*M_d;  d' = C*M_u;  P' = -S*M_P;  R' = -S*M_R      (note u/d SWAP)
//   ev[w-1] = M_d (delta-collapse at next site);  ev[7] = d_7 + P_7.
// Init (site 0, direct from a a-dagger): u=C, d=C*K, P=-S*A2, R=-S*B2.
// Validated vs Heisenberg (generic 2q) + brute-force statevector (2q, 3q).
__global__ __launch_bounds__(256) void qlstm_kernel(
    const float* __restrict__ X,  const float* __restrict__ Wq, const float* __restrict__ bq,
    const float* __restrict__ pf, const float* __restrict__ pi_, const float* __restrict__ pg,
    const float* __restrict__ po, const float* __restrict__ Wf, const float* __restrict__ bf,
    const float* __restrict__ Wi, const float* __restrict__ bi, const float* __restrict__ Wg,
    const float* __restrict__ bg, const float* __restrict__ Wo, const float* __restrict__ bo,
    float* __restrict__ out)
{
  __shared__ float gsh[2][128 * 6];   // gates pad-6 (conflict-light), dbuf by t&1

  const int tid  = threadIdx.x;
  const int lane = tid & 63;
  const int wv   = tid >> 6;
  const int b    = blockIdx.x;

  const float* gW = (wv == 0) ? Wf : (wv == 1) ? Wi : (wv == 2) ? Wg : Wo;
  const float* gB = (wv == 0) ? bf : (wv == 1) ? bi : (wv == 2) ? bg : bo;
  const float* gP = (wv == 0) ? pf : (wv == 1) ? pi_ : (wv == 2) ? pg : po;

  // ---- one-time register preloads ----
  float wqr[8][4];                    // Wq rows 0..7 (rows 8..31 dead)
#pragma unroll
  for (int w = 0; w < 8; ++w)
#pragma unroll
    for (int k = 0; k < 4; ++k) wqr[w][k] = Wq[w * 256 + lane + 64 * k];

  // wire owned by this lane after reduce8_scatter: w_own = 4b0 + 2b1 + b2
  const int w_own = 4 * (lane & 1) + 2 * ((lane >> 1) & 1) + ((lane >> 2) & 1);
  const float bq_own = bq[w_own];

  float wgr[2][8];                    // gate weights W[h][w], h = lane, lane+64
#pragma unroll
  for (int r = 0; r < 2; ++r)
#pragma unroll
    for (int w = 0; w < 8; ++w) wgr[r][w] = gW[(lane + 64 * r) * 8 + w];
  float br2[2] = { gB[lane], gB[lane + 64] };

  // TM per-wire constants (FULL angles, t-invariant)
  float C1[8], S1[8], cb0[8], sb0[8];
#pragma unroll
  for (int w = 0; w < 8; ++w) {
    float th0 = gP[w], th1 = gP[8 + w];
    cb0[w] = cosf(th0); sb0[w] = sinf(th0);
    C1[w]  = cosf(th1); S1[w]  = sinf(th1);
  }

  float c0r = 0.0f, c1r = 0.0f, h0r = 0.0f, h1r = 0.0f;

  // x prefetch
  float nx0 = X[(size_t)b * IN_DIM + lane];
  float nx1 = X[(size_t)b * IN_DIM + lane + 64];

#pragma unroll 1
  for (int t = 0; t < SEQ; ++t) {
    float xv0 = nx0, xv1 = nx1;
    if (t + 1 < SEQ) {
      const float* xn = X + ((size_t)(t + 1) * BATCH + b) * IN_DIM;
      nx0 = xn[lane]; nx1 = xn[lane + 64];
    }

    // ---- q_in partials + reduce-scatter; owner-lane sincos; readlane bcast ----
    float qp[8];
#pragma unroll
    for (int w = 0; w < 8; ++w)
      qp[w] = xv0 * wqr[w][0] + xv1 * wqr[w][1] + h0r * wqr[w][2] + h1r * wqr[w][3];
    float z = reduce8_scatter(qp, lane) + bq_own;
    float sz, cz;
    __sincosf(z, &sz, &cz);           // FULL angle: TM needs cos q, sin q

    // wire w lives on lane rev3(w): {0,4,2,6,1,5,3,7}
    float cq[8], sq[8];
    cq[0] = __shfl(cz, 0, 64); sq[0] = __shfl(sz, 0, 64);
    cq[1] = __shfl(cz, 4, 64); sq[1] = __shfl(sz, 4, 64);
    cq[2] = __shfl(cz, 2, 64); sq[2] = __shfl(sz, 2, 64);
    cq[3] = __shfl(cz, 6, 64); sq[3] = __shfl(sz, 6, 64);
    cq[4] = __shfl(cz, 1, 64); sq[4] = __shfl(sz, 1, 64);
    cq[5] = __shfl(cz, 5, 64); sq[5] = __shfl(sz, 5, 64);
    cq[6] = __shfl(cz, 3, 64); sq[6] = __shfl(sz, 3, 64);
    cq[7] = __shfl(cz, 7, 64); sq[7] = __shfl(sz, 7, 64);

    // ---- transfer-matrix chain (exact; wave-uniform) ----
    float ev[8];
    float u, d, P, R;
    {
      float K0  = cb0[0] * cq[0];
      float A20 = sb0[0] * cq[0];
      u = C1[0];
      d = C1[0] * K0;
      P = -S1[0] * A20;
      R = -S1[0] * sq[0];
    }
#pragma unroll
    for (int w = 1; w < 8; ++w) {
      float Kw  = cb0[w] * cq[w];
      float A2w = sb0[w] * cq[w];
      float B2w = sq[w];
      float Mu = Kw * u - B2w * R;
      float Md = d + A2w * P;
      float MP = A2w * d + P;
      float MR = B2w * u + Kw * R;
      ev[w - 1] = Md;                 // ev[w-1] = d_{w-1} + A2_w * P_{w-1}
      u = C1[w] * Md;                 // u' = C * M_d   (swap!)
      d = C1[w] * Mu;                 // d' = C * M_u
      P = -S1[w] * MP;
      R = -S1[w] * MR;
    }
    ev[7] = d + P;                    // last site: full sum

    // ---- gate linear (8 -> 128, weights + evs in regs) + activation ----
    float* gbuf = gsh[t & 1];
#pragma unroll
    for (int r = 0; r < 2; ++r) {
      float acc = br2[r];
#pragma unroll
      for (int w = 0; w < 8; ++w) acc += ev[w] * wgr[r][w];
      gbuf[(lane + 64 * r) * 6 + wv] = (wv == 2) ? tanh_f(acc) : sigmoid_f(acc);
    }
    __syncthreads();

    // ---- LSTM cell update, replicated in every wave (h,c stay in regs) ----
    float2 fi0 = *(const float2*)&gbuf[lane * 6];
    float2 go0 = *(const float2*)&gbuf[lane * 6 + 2];
    float2 fi1 = *(const float2*)&gbuf[(lane + 64) * 6];
    float2 go1 = *(const float2*)&gbuf[(lane + 64) * 6 + 2];
    c0r = fi0.x * c0r + fi0.y * go0.x;
    c1r = fi1.x * c1r + fi1.y * go1.x;
    h0r = go0.y * tanh_f(c0r);
    h1r = go1.y * tanh_f(c1r);

    if (wv == 0) {
      float* op = out + ((size_t)t * BATCH + b) * HID;
      op[lane] = h0r; op[lane + 64] = h1r;
    }
  }

  if (wv == 0) {
    size_t base = (size_t)SEQ * BATCH * HID;
    out[base + (size_t)b * HID + lane] = h0r;
    out[base + (size_t)b * HID + lane + 64] = h1r;
    out[base + (size_t)BATCH * HID + (size_t)b * HID + lane] = c0r;
    out[base + (size_t)BATCH * HID + (size_t)b * HID + lane + 64] = c1r;
  }
}

extern "C" void kernel_launch(void* const* d_in, const int* in_sizes, int n_in,
                              void* d_out, int out_size, void* d_ws, size_t ws_size,
                              hipStream_t stream) {
  (void)in_sizes; (void)n_in; (void)out_size; (void)d_ws; (void)ws_size;
  const float* X   = (const float*)d_in[0];
  const float* Wq  = (const float*)d_in[1];
  const float* bq  = (const float*)d_in[2];
  const float* pf  = (const float*)d_in[3];
  const float* pi_ = (const float*)d_in[4];
  const float* pg  = (const float*)d_in[5];
  const float* po  = (const float*)d_in[6];
  const float* Wf  = (const float*)d_in[7];
  const float* bf  = (const float*)d_in[8];
  const float* Wi  = (const float*)d_in[9];
  const float* bi  = (const float*)d_in[10];
  const float* Wg  = (const float*)d_in[11];
  const float* bg  = (const float*)d_in[12];
  const float* Wo  = (const float*)d_in[13];
  const float* bo  = (const float*)d_in[14];
  float* out = (float*)d_out;

  qlstm_kernel<<<BATCH, 256, 0, stream>>>(X, Wq, bq, pf, pi_, pg, po,
                                          Wf, bf, Wi, bi, Wg, bg, Wo, bo, out);
}

// Round 5
// 247.147 us; speedup vs baseline: 2.5285x; 1.0427x over previous
//
#include <hip/hip_runtime.h>

#define SEQ 128
#define BATCH 512
#define IN_DIM 128
#define HID 128

typedef float vf2 __attribute__((ext_vector_type(2)));

__device__ __forceinline__ float sigmoid_f(float x) { return 1.0f / (1.0f + __expf(-x)); }
__device__ __forceinline__ float tanh_f(float x) { return 1.0f - 2.0f / (__expf(2.0f * x) + 1.0f); }

// DPP quad_perm lane swaps (VALU pipe): xor1 = [1,0,3,2] = 0xB1, xor2 = [2,3,0,1] = 0x4E
__device__ __forceinline__ float dpp_xor1(float x) {
  return __int_as_float(__builtin_amdgcn_mov_dpp(__float_as_int(x), 0xB1, 0xF, 0xF, true));
}
__device__ __forceinline__ float dpp_xor2(float x) {
  return __int_as_float(__builtin_amdgcn_mov_dpp(__float_as_int(x), 0x4E, 0xF, 0xF, true));
}
__device__ __forceinline__ float readlane_f(float x, int l) {
  return __int_as_float(__builtin_amdgcn_readlane(__float_as_int(x), l));
}

// Reduce-scatter of 8 per-lane partials: lane (b2 b1 b0 = low bits) ends up
// holding the full wave-sum of v[4*b0 + 2*b1 + b2]. 4 ds shuffles + 6 DPP.
__device__ __forceinline__ float reduce8_scatter(const float v[8], int lane) {
  const bool c0 = lane & 1, c1 = lane & 2, c2 = lane & 4;
  float w[4];
#pragma unroll
  for (int k = 0; k < 4; ++k) {
    float mine = c0 ? v[4 + k] : v[k];
    float send = c0 ? v[k] : v[4 + k];
    w[k] = mine + dpp_xor1(send);
  }
  float u[2];
#pragma unroll
  for (int k = 0; k < 2; ++k) {
    float mine = c1 ? w[2 + k] : w[k];
    float send = c1 ? w[k] : w[2 + k];
    u[k] = mine + dpp_xor2(send);
  }
  float mine = c2 ? u[1] : u[0];
  float send = c2 ? u[0] : u[1];
  float z = mine + __shfl_xor(send, 4, 64);
  z += __shfl_xor(z, 8, 64);
  z += __shfl_xor(z, 16, 64);
  z += __shfl_xor(z, 32, 64);
  return z;
}

// One block per batch element; wave wv handles gate wv (f,i,g,o).
// Quantum circuit: exact 4-dim transfer-matrix recursion (validated R4):
//   state (u,d,P,R); per wire: K=cos(b0)cos(q), A2=sin(b0)cos(q), B2=sin(q),
//   C=cos(b1), S=sin(b1):
//     Mu=K*u-B2*R; Md=d+A2*P; MP=A2*d+P; MR=B2*u+K*R
//     u'=C*Md; d'=C*Mu; P'=-S*MP; R'=-S*MR   (u/d swap)
//   ev[w-1]=Md (consumed by fused gate GEMM immediately); ev[7]=d_7+P_7.
__global__ __launch_bounds__(256) void qlstm_kernel(
    const float* __restrict__ X,  const float* __restrict__ Wq, const float* __restrict__ bq,
    const float* __restrict__ pf, const float* __restrict__ pi_, const float* __restrict__ pg,
    const float* __restrict__ po, const float* __restrict__ Wf, const float* __restrict__ bf,
    const float* __restrict__ Wi, const float* __restrict__ bi, const float* __restrict__ Wg,
    const float* __restrict__ bg, const float* __restrict__ Wo, const float* __restrict__ bo,
    float* __restrict__ out)
{
  __shared__ float gsh[2][128 * 6];   // gates pad-6, dbuf by t&1

  const int tid  = threadIdx.x;
  const int lane = tid & 63;
  const int wv   = tid >> 6;
  const int b    = blockIdx.x;

  const float* gW = (wv == 0) ? Wf : (wv == 1) ? Wi : (wv == 2) ? Wg : Wo;
  const float* gB = (wv == 0) ? bf : (wv == 1) ? bi : (wv == 2) ? bg : bo;
  const float* gP = (wv == 0) ? pf : (wv == 1) ? pi_ : (wv == 2) ? pg : po;

  // ---- one-time register preloads ----
  // Wq rows 0..7 (rows 8..31 dead), packed over wire pairs (2p, 2p+1)
  vf2 wq2[4][4];
#pragma unroll
  for (int p = 0; p < 4; ++p)
#pragma unroll
    for (int k = 0; k < 4; ++k) {
      wq2[p][k].x = Wq[(2 * p)     * 256 + lane + 64 * k];
      wq2[p][k].y = Wq[(2 * p + 1) * 256 + lane + 64 * k];
    }

  // wire owned by this lane after reduce8_scatter: w_own = 4b0 + 2b1 + b2
  const int w_own = 4 * (lane & 1) + 2 * ((lane >> 1) & 1) + ((lane >> 2) & 1);
  const float bq_own = bq[w_own];

  // gate weights packed over the two h's this lane owns: (h=lane, h=lane+64)
  vf2 wg2[8];
#pragma unroll
  for (int w = 0; w < 8; ++w) {
    wg2[w].x = gW[lane * 8 + w];
    wg2[w].y = gW[(lane + 64) * 8 + w];
  }
  vf2 br2v; br2v.x = gB[lane]; br2v.y = gB[lane + 64];

  // TM per-wire constants (FULL angles, t-invariant); (cb0,sb0) packed
  vf2 cbsb[8];
  float C1[8], S1[8];
#pragma unroll
  for (int w = 0; w < 8; ++w) {
    float th0 = gP[w], th1 = gP[8 + w];
    cbsb[w].x = cosf(th0); cbsb[w].y = sinf(th0);
    C1[w] = cosf(th1); S1[w] = sinf(th1);
  }

  float c0r = 0.0f, c1r = 0.0f, h0r = 0.0f, h1r = 0.0f;

  // x prefetch
  float nx0 = X[(size_t)b * IN_DIM + lane];
  float nx1 = X[(size_t)b * IN_DIM + lane + 64];

#pragma unroll 1
  for (int t = 0; t < SEQ; ++t) {
    float xv0 = nx0, xv1 = nx1;
    if (t + 1 < SEQ) {
      const float* xn = X + ((size_t)(t + 1) * BATCH + b) * IN_DIM;
      nx0 = xn[lane]; nx1 = xn[lane + 64];
    }

    // ---- q_in partials (packed over wire pairs) + reduce-scatter ----
    vf2 qp2[4];
#pragma unroll
    for (int p = 0; p < 4; ++p)
      qp2[p] = xv0 * wq2[p][0] + xv1 * wq2[p][1] + h0r * wq2[p][2] + h1r * wq2[p][3];
    float v[8];
#pragma unroll
    for (int p = 0; p < 4; ++p) { v[2 * p] = qp2[p].x; v[2 * p + 1] = qp2[p].y; }
    float z = reduce8_scatter(v, lane) + bq_own;
    float sz, cz;
    __sincosf(z, &sz, &cz);           // FULL angle: TM needs cos q, sin q

    // wire w lives on lane rev3(w): {0,4,2,6,1,5,3,7} -> readlane (SGPR bcast)
    float cq[8], sq[8];
    cq[0] = readlane_f(cz, 0); sq[0] = readlane_f(sz, 0);
    cq[1] = readlane_f(cz, 4); sq[1] = readlane_f(sz, 4);
    cq[2] = readlane_f(cz, 2); sq[2] = readlane_f(sz, 2);
    cq[3] = readlane_f(cz, 6); sq[3] = readlane_f(sz, 6);
    cq[4] = readlane_f(cz, 1); sq[4] = readlane_f(sz, 1);
    cq[5] = readlane_f(cz, 5); sq[5] = readlane_f(sz, 5);
    cq[6] = readlane_f(cz, 3); sq[6] = readlane_f(sz, 3);
    cq[7] = readlane_f(cz, 7); sq[7] = readlane_f(sz, 7);

    // ---- transfer-matrix chain with FUSED gate GEMM ----
    vf2 acc = br2v;
    float u, d, P, R;
    {
      vf2 KA0 = cbsb[0] * cq[0];      // (K0, A2_0) pk_mul
      u = C1[0];
      d = C1[0] * KA0.x;
      P = -S1[0] * KA0.y;
      R = -S1[0] * sq[0];
    }
#pragma unroll
    for (int w = 1; w < 8; ++w) {
      vf2 KA = cbsb[w] * cq[w];       // (K, A2) pk_mul
      float K = KA.x, A2 = KA.y, B2 = sq[w];
      float Md = fmaf(A2, P, d);      // == ev[w-1]
      float MP = fmaf(A2, d, P);
      float Mu = fmaf(K, u, -(B2 * R));
      float MR = fmaf(B2, u, K * R);
      acc = acc + Md * wg2[w - 1];    // fused GEMM (pk_fma)
      vf2 ud2; ud2.x = Md; ud2.y = Mu;
      vf2 PR2; PR2.x = MP; PR2.y = MR;
      ud2 = C1[w] * ud2;              // (u', d') pk_mul
      PR2 = -S1[w] * PR2;             // (P', R') pk_mul
      u = ud2.x; d = ud2.y; P = PR2.x; R = PR2.y;
    }
    float ev7 = d + P;                // last site: full sum
    acc = acc + ev7 * wg2[7];

    // ---- activation + gate exchange ----
    float* gbuf = gsh[t & 1];
    float g0 = (wv == 2) ? tanh_f(acc.x) : sigmoid_f(acc.x);
    float g1 = (wv == 2) ? tanh_f(acc.y) : sigmoid_f(acc.y);
    gbuf[lane * 6 + wv] = g0;
    gbuf[(lane + 64) * 6 + wv] = g1;
    __syncthreads();

    // ---- LSTM cell update, replicated in every wave (h,c stay in regs) ----
    float2 fi0 = *(const float2*)&gbuf[lane * 6];
    float2 go0 = *(const float2*)&gbuf[lane * 6 + 2];
    float2 fi1 = *(const float2*)&gbuf[(lane + 64) * 6];
    float2 go1 = *(const float2*)&gbuf[(lane + 64) * 6 + 2];
    c0r = fi0.x * c0r + fi0.y * go0.x;
    c1r = fi1.x * c1r + fi1.y * go1.x;
    h0r = go0.y * tanh_f(c0r);
    h1r = go1.y * tanh_f(c1r);

    if (wv == 0) {
      float* op = out + ((size_t)t * BATCH + b) * HID;
      op[lane] = h0r; op[lane + 64] = h1r;
    }
  }

  if (wv == 0) {
    size_t base = (size_t)SEQ * BATCH * HID;
    out[base + (size_t)b * HID + lane] = h0r;
    out[base + (size_t)b * HID + lane + 64] = h1r;
    out[base + (size_t)BATCH * HID + (size_t)b * HID + lane] = c0r;
    out[base + (size_t)BATCH * HID + (size_t)b * HID + lane + 64] = c1r;
  }
}

extern "C" void kernel_launch(void* const* d_in, const int* in_sizes, int n_in,
                              void* d_out, int out_size, void* d_ws, size_t ws_size,
                              hipStream_t stream) {
  (void)in_sizes; (void)n_in; (void)out_size; (void)d_ws; (void)ws_size;
  const float* X   = (const float*)d_in[0];
  const float* Wq  = (const float*)d_in[1];
  const float* bq  = (const float*)d_in[2];
  const float* pf  = (const float*)d_in[3];
  const float* pi_ = (const float*)d_in[4];
  const float* pg  = (const float*)d_in[5];
  const float* po  = (const float*)d_in[6];
  const float* Wf  = (const float*)d_in[7];
  const float* bf  = (const float*)d_in[8];
  const float* Wi  = (const float*)d_in[9];
  const float* bi  = (const float*)d_in[10];
  const float* Wg  = (const float*)d_in[11];
  const float* bg  = (const float*)d_in[12];
  const float* Wo  = (const float*)d_in[13];
  const float* bo  = (const float*)d_in[14];
  float* out = (float*)d_out;

  qlstm_kernel<<<BATCH, 256, 0, stream>>>(X, Wq, bq, pf, pi_, pg, po,
                                          Wf, bf, Wi, bi, Wg, bg, Wo, bo, out);
}